// Round 1
// baseline (448.675 us; speedup 1.0000x reference)
//
#include <hip/hip_runtime.h>
#include <hip/hip_bf16.h>
#include <math.h>

#define SEQ   2048
#define BATCH 32
#define DIM   1024
#define MROWS (SEQ*BATCH)   // 65536 rows, r = s*32 + b
#define NT    8             // 1024 / 128 N-tiles
#define NCH   16            // context s-chunks

typedef __attribute__((ext_vector_type(8))) short short8;
typedef __attribute__((ext_vector_type(4))) float f32x4;

__device__ __forceinline__ unsigned short f2bf(float f) {
  unsigned u = __builtin_bit_cast(unsigned, f);
  u += 0x7FFFu + ((u >> 16) & 1u);      // round-to-nearest-even
  return (unsigned short)(u >> 16);
}

// ---------------- W_enc fp32 -> bf16 ----------------
__global__ __launch_bounds__(256) void wconv_k(const float* __restrict__ W,
                                               unsigned short* __restrict__ Wbf) {
  int i = blockIdx.x * 256 + threadIdx.x;          // float4 units, 262144 total
  float4 v = *reinterpret_cast<const float4*>(&W[(size_t)i * 4]);
  ushort4 o;
  o.x = f2bf(v.x); o.y = f2bf(v.y); o.z = f2bf(v.z); o.w = f2bf(v.w);
  *reinterpret_cast<ushort4*>(&Wbf[(size_t)i * 4]) = o;
}

// ---------------- q[b,e] = sum_d dh[b,d] * W_dec[e,d]  (partials over d-chunks) --------
__global__ __launch_bounds__(256) void qpart_k(const float* __restrict__ dh,
                                               const float* __restrict__ Wd,
                                               float* __restrict__ qpart) {
  const int bx = blockIdx.x;        // 32 blocks
  const int eb = bx & 3;            // 4 e-blocks of 256
  const int dc = bx >> 2;           // 8 d-chunks of 128
  __shared__ float ldh[BATCH][128];
  const int tid = threadIdx.x;
#pragma unroll
  for (int i = 0; i < 4; ++i) {
    int idx = tid + i * 256;        // float4 index over 32*128 = 4096 floats
    int bb = idx >> 5, d4 = idx & 31;
    float4 v = *reinterpret_cast<const float4*>(&dh[(size_t)bb * DIM + dc * 128 + d4 * 4]);
    *reinterpret_cast<float4*>(&ldh[bb][d4 * 4]) = v;
  }
  __syncthreads();
  const int e = eb * 256 + tid;
  float acc[BATCH];
#pragma unroll
  for (int b = 0; b < BATCH; ++b) acc[b] = 0.f;
  for (int d4 = 0; d4 < 32; ++d4) {
    float4 w = *reinterpret_cast<const float4*>(&Wd[(size_t)e * DIM + dc * 128 + d4 * 4]);
#pragma unroll
    for (int b = 0; b < BATCH; ++b) {
      float4 h = *reinterpret_cast<const float4*>(&ldh[b][d4 * 4]);
      acc[b] += w.x * h.x + w.y * h.y + w.z * h.z + w.w * h.w;
    }
  }
#pragma unroll
  for (int b = 0; b < BATCH; ++b)
    qpart[((size_t)dc * BATCH + b) * DIM + e] = acc[b];
}

__global__ __launch_bounds__(256) void qred_k(const float* __restrict__ qpart,
                                              float* __restrict__ q) {
  int i = blockIdx.x * 256 + threadIdx.x;          // 32768
  float s = 0.f;
#pragma unroll
  for (int dc = 0; dc < 8; ++dc) s += qpart[(size_t)dc * 32768 + i];
  q[i] = s;
}

// ---------------- fused GEMM: keys -> tanh -> dot(V) -> logits partials ----------------
// C[r][e] = sum_d enc[r][d]*W[e][d]; partial[r][nt] = sum_{e in tile} tanh(C+q[b][e])*V[e]
__global__ __launch_bounds__(256) void gemm_fused(const float* __restrict__ enc,
                                                  const unsigned short* __restrict__ Wbf,
                                                  const float* __restrict__ q,
                                                  const float* __restrict__ V,
                                                  float* __restrict__ lpart) {
  __shared__ unsigned short As[128][56];   // stride 112 B: 16B-aligned, 2-way banks (free)
  __shared__ unsigned short Bs[128][56];
  __shared__ float red[2][128];

  const int bx = blockIdx.x;
  const int nt = bx & (NT - 1);
  const int mt = bx >> 3;
  const int row0 = mt * 128, col0 = nt * 128;
  const int tid = threadIdx.x;
  const int lane = tid & 63;
  const int w = tid >> 6;
  const int wr = w >> 1, wc = w & 1;
  const int fr = lane & 15, kq = lane >> 4;

  f32x4 acc[4][4];
#pragma unroll
  for (int i = 0; i < 4; ++i)
#pragma unroll
    for (int j = 0; j < 4; ++j) acc[i][j] = (f32x4)(0.f);

  const int trow = tid >> 3;   // 0..31
  const int tc4 = tid & 7;     // 0..7

  for (int kt = 0; kt < DIM / 32; ++kt) {
    const int k0 = kt * 32;
    __syncthreads();
#pragma unroll
    for (int it = 0; it < 4; ++it) {
      const int r = trow + it * 32;
      float4 va = *reinterpret_cast<const float4*>(
          &enc[(size_t)(row0 + r) * DIM + k0 + tc4 * 4]);
      ushort4 ua;
      ua.x = f2bf(va.x); ua.y = f2bf(va.y); ua.z = f2bf(va.z); ua.w = f2bf(va.w);
      *reinterpret_cast<ushort4*>(&As[r][tc4 * 4]) = ua;
      ushort4 ub = *reinterpret_cast<const ushort4*>(
          &Wbf[(size_t)(col0 + r) * DIM + k0 + tc4 * 4]);
      *reinterpret_cast<ushort4*>(&Bs[r][tc4 * 4]) = ub;
    }
    __syncthreads();

    short8 af[4], bf[4];
#pragma unroll
    for (int mf = 0; mf < 4; ++mf)
      af[mf] = *reinterpret_cast<const short8*>(&As[wr * 64 + mf * 16 + fr][kq * 8]);
#pragma unroll
    for (int nf = 0; nf < 4; ++nf)
      bf[nf] = *reinterpret_cast<const short8*>(&Bs[wc * 64 + nf * 16 + fr][kq * 8]);
#pragma unroll
    for (int mf = 0; mf < 4; ++mf)
#pragma unroll
      for (int nf = 0; nf < 4; ++nf)
        acc[mf][nf] = __builtin_amdgcn_mfma_f32_16x16x32_bf16(af[mf], bf[nf],
                                                              acc[mf][nf], 0, 0, 0);
  }

  // Epilogue: t = tanh(C + q[b][e]) * V[e], reduce over this block's 128 e's per row.
#pragma unroll
  for (int mf = 0; mf < 4; ++mf) {
#pragma unroll
    for (int reg = 0; reg < 4; ++reg) {
      const int m_loc = wr * 64 + mf * 16 + kq * 4 + reg;
      const int b = m_loc & 31;     // row0 % 32 == 0, so b = (row0+m_loc)&31
      float part = 0.f;
#pragma unroll
      for (int nf = 0; nf < 4; ++nf) {
        const int e = col0 + wc * 64 + nf * 16 + fr;
        float c = acc[mf][nf][reg];
        part += tanhf(c + q[b * DIM + e]) * V[e];
      }
#pragma unroll
      for (int off = 8; off >= 1; off >>= 1) part += __shfl_xor(part, off);
      if (fr == 0) red[wc][m_loc] = part;
    }
  }
  __syncthreads();
  if (tid < 128)
    lpart[(size_t)(row0 + tid) * NT + nt] = red[0][tid] + red[1][tid];
}

// ---------------- softmax over seq per batch ----------------
__global__ __launch_bounds__(256) void softmax_k(const float* __restrict__ lpart,
                                                 float* __restrict__ alpha) {
  const int b = blockIdx.x;
  __shared__ float lv[SEQ];
  __shared__ float sred[4];
  const int tid = threadIdx.x;
  float mx = -1e30f;
  for (int s = tid; s < SEQ; s += 256) {
    const float* p = &lpart[(size_t)(s * BATCH + b) * NT];
    float v = 0.f;
#pragma unroll
    for (int t = 0; t < NT; ++t) v += p[t];
    lv[s] = v;
    mx = fmaxf(mx, v);
  }
#pragma unroll
  for (int off = 32; off >= 1; off >>= 1) mx = fmaxf(mx, __shfl_xor(mx, off));
  if ((tid & 63) == 0) sred[tid >> 6] = mx;
  __syncthreads();
  mx = fmaxf(fmaxf(sred[0], sred[1]), fmaxf(sred[2], sred[3]));
  __syncthreads();
  float sm = 0.f;
  for (int s = tid; s < SEQ; s += 256) {
    float e = expf(lv[s] - mx);
    lv[s] = e;
    sm += e;
  }
#pragma unroll
  for (int off = 32; off >= 1; off >>= 1) sm += __shfl_xor(sm, off);
  if ((tid & 63) == 0) sred[tid >> 6] = sm;
  __syncthreads();
  const float inv = 1.f / (sred[0] + sred[1] + sred[2] + sred[3]);
  for (int s = tid; s < SEQ; s += 256)
    alpha[(size_t)b * SEQ + s] = lv[s] * inv;
}

// ---------------- context partials: sum_s alpha[b,s]*enc[s,b,:] ----------------
__global__ __launch_bounds__(256) void ctx_part_k(const float* __restrict__ enc,
                                                  const float* __restrict__ alpha,
                                                  float* __restrict__ cpart) {
  const int blk = blockIdx.x;
  const int b = blk & 31;
  const int ch = blk >> 5;
  const int tid = threadIdx.x;                 // float4 lane over DIM
  const int s0 = ch * (SEQ / NCH);
  float4 acc = make_float4(0.f, 0.f, 0.f, 0.f);
#pragma unroll 4
  for (int i = 0; i < SEQ / NCH; ++i) {
    const int s = s0 + i;
    const float a = alpha[(size_t)b * SEQ + s];
    float4 v = *reinterpret_cast<const float4*>(
        &enc[((size_t)s * BATCH + b) * DIM + tid * 4]);
    acc.x += a * v.x; acc.y += a * v.y; acc.z += a * v.z; acc.w += a * v.w;
  }
  *reinterpret_cast<float4*>(&cpart[((size_t)ch * BATCH + b) * DIM + tid * 4]) = acc;
}

__global__ __launch_bounds__(256) void ctxred_k(const float* __restrict__ cpart,
                                                float* __restrict__ out) {
  int i = blockIdx.x * 256 + threadIdx.x;      // 32768
  float s = 0.f;
#pragma unroll
  for (int ch = 0; ch < NCH; ++ch) s += cpart[(size_t)ch * 32768 + i];
  out[i] = s;
}

extern "C" void kernel_launch(void* const* d_in, const int* in_sizes, int n_in,
                              void* d_out, int out_size, void* d_ws, size_t ws_size,
                              hipStream_t stream) {
  const float* dh   = (const float*)d_in[0];   // (32,1,1024)
  const float* enc  = (const float*)d_in[1];   // (2048,32,1024)
  const float* Wenc = (const float*)d_in[2];   // (1024,1024)
  const float* Wdec = (const float*)d_in[3];   // (1024,1024)
  const float* Vatt = (const float*)d_in[4];   // (1,1024)
  float* out = (float*)d_out;                  // [0,32768) context, [32768,98304) alpha

  float* ws = (float*)d_ws;
  float* q      = ws;                               // 32768 f
  float* qpart  = ws + 32768;                       // 262144 f
  unsigned short* Wbf = (unsigned short*)(ws + 294912); // 1M bf16 (2 MB)
  float* lpart  = ws + 819200;                      // 65536*8 f (2 MB)
  float* cpart  = ws + 1343488;                     // 16*32768 f (2 MB)

  wconv_k   <<<dim3(1024),      dim3(256), 0, stream>>>(Wenc, Wbf);
  qpart_k   <<<dim3(32),        dim3(256), 0, stream>>>(dh, Wdec, qpart);
  qred_k    <<<dim3(128),       dim3(256), 0, stream>>>(qpart, q);
  gemm_fused<<<dim3(MROWS/128 * NT), dim3(256), 0, stream>>>(enc, Wbf, q, Vatt, lpart);
  softmax_k <<<dim3(BATCH),     dim3(256), 0, stream>>>(lpart, out + 32768);
  ctx_part_k<<<dim3(BATCH*NCH), dim3(256), 0, stream>>>(enc, out + 32768, cpart);
  ctxred_k  <<<dim3(128),       dim3(256), 0, stream>>>(cpart, out);
}

// Round 2
// 408.560 us; speedup vs baseline: 1.0982x; 1.0982x over previous
//
#include <hip/hip_runtime.h>
#include <hip/hip_bf16.h>
#include <math.h>

#define SEQ   2048
#define BATCH 32
#define DIM   1024
#define MROWS (SEQ*BATCH)   // 65536 rows, r = s*32 + b
#define NT    8             // 1024 / 128 N-tiles
#define NCH   16            // context s-chunks

typedef __attribute__((ext_vector_type(8))) short short8;
typedef __attribute__((ext_vector_type(8))) unsigned short u16x8;
typedef __attribute__((ext_vector_type(4))) float f32x4;

__device__ __forceinline__ unsigned short f2bf(float f) {
  unsigned u = __builtin_bit_cast(unsigned, f);
  u += 0x7FFFu + ((u >> 16) & 1u);      // round-to-nearest-even
  return (unsigned short)(u >> 16);
}

// async global -> LDS, 16 B per lane (dest = wave-uniform base + lane*16)
__device__ __forceinline__ void gl16(const unsigned short* g, unsigned short* l) {
  __builtin_amdgcn_global_load_lds(
      (const __attribute__((address_space(1))) unsigned int*)g,
      (__attribute__((address_space(3))) unsigned int*)l, 16, 0, 0);
}

// ---------------- fp32 -> bf16 bulk convert (8 elems/thread) ----------------
__global__ __launch_bounds__(256) void conv_bf16_k(const float* __restrict__ src,
                                                   unsigned short* __restrict__ dst) {
  size_t i = ((size_t)blockIdx.x * 256 + threadIdx.x) * 8;
  float4 a = *reinterpret_cast<const float4*>(src + i);
  float4 b = *reinterpret_cast<const float4*>(src + i + 4);
  u16x8 o;
  o[0] = f2bf(a.x); o[1] = f2bf(a.y); o[2] = f2bf(a.z); o[3] = f2bf(a.w);
  o[4] = f2bf(b.x); o[5] = f2bf(b.y); o[6] = f2bf(b.z); o[7] = f2bf(b.w);
  *reinterpret_cast<u16x8*>(dst + i) = o;
}

// ---------------- q[b,e] = sum_d dh[b,d] * W_dec[e,d]  (partials over d-chunks) --------
__global__ __launch_bounds__(256) void qpart_k(const float* __restrict__ dh,
                                               const float* __restrict__ Wd,
                                               float* __restrict__ qpart) {
  const int bx = blockIdx.x;        // 32 blocks
  const int eb = bx & 3;            // 4 e-blocks of 256
  const int dc = bx >> 2;           // 8 d-chunks of 128
  __shared__ float ldh[BATCH][128];
  const int tid = threadIdx.x;
#pragma unroll
  for (int i = 0; i < 4; ++i) {
    int idx = tid + i * 256;
    int bb = idx >> 5, d4 = idx & 31;
    float4 v = *reinterpret_cast<const float4*>(&dh[(size_t)bb * DIM + dc * 128 + d4 * 4]);
    *reinterpret_cast<float4*>(&ldh[bb][d4 * 4]) = v;
  }
  __syncthreads();
  const int e = eb * 256 + tid;
  float acc[BATCH];
#pragma unroll
  for (int b = 0; b < BATCH; ++b) acc[b] = 0.f;
  for (int d4 = 0; d4 < 32; ++d4) {
    float4 w = *reinterpret_cast<const float4*>(&Wd[(size_t)e * DIM + dc * 128 + d4 * 4]);
#pragma unroll
    for (int b = 0; b < BATCH; ++b) {
      float4 h = *reinterpret_cast<const float4*>(&ldh[b][d4 * 4]);
      acc[b] += w.x * h.x + w.y * h.y + w.z * h.z + w.w * h.w;
    }
  }
#pragma unroll
  for (int b = 0; b < BATCH; ++b)
    qpart[((size_t)dc * BATCH + b) * DIM + e] = acc[b];
}

__global__ __launch_bounds__(256) void qred_k(const float* __restrict__ qpart,
                                              float* __restrict__ q) {
  int i = blockIdx.x * 256 + threadIdx.x;
  float s = 0.f;
#pragma unroll
  for (int dc = 0; dc < 8; ++dc) s += qpart[(size_t)dc * 32768 + i];
  q[i] = s;
}

// ---------------- fused GEMM v2: bf16 A + global_load_lds + XOR swizzle ----------------
// A = enc bf16 [65536][1024], B = W_enc bf16 [1024][1024] (row e, col d)
// C[r][e] = sum_d A[r][d]*B[e][d]; lpart[r][nt] = sum_{e in tile} tanh(C+q[b][e])*V[e]
__global__ __launch_bounds__(256) void gemm_fused2(const unsigned short* __restrict__ A,
                                                   const unsigned short* __restrict__ B,
                                                   const float* __restrict__ q,
                                                   const float* __restrict__ V,
                                                   float* __restrict__ lpart) {
  __shared__ unsigned short As[128 * 32];   // linear [row][32], chunks XOR-swizzled
  __shared__ unsigned short Bs[128 * 32];
  __shared__ float red[2][128];

  const int bid = blockIdx.x;
  // XCD-aware bijective swizzle: 4096 blocks, 8 XCDs, 512 contiguous wgs each
  const int wg = (bid & 7) * 512 + (bid >> 3);
  const int mt = wg >> 3, nt = wg & 7;
  const int row0 = mt * 128, col0 = nt * 128;
  const int tid = threadIdx.x;
  const int lane = tid & 63;
  const int w = tid >> 6;
  const int wr = w >> 1, wc = w & 1;
  const int fr = lane & 15, kq = lane >> 4;

  f32x4 acc[4][4];
#pragma unroll
  for (int i = 0; i < 4; ++i)
#pragma unroll
    for (int j = 0; j < 4; ++j) acc[i][j] = (f32x4)(0.f);

  // staging geometry: 512 slots of 16 B per tile; iter t: idx = t*256 + tid
  // row = idx>>2, lds slot c' = idx&3 holds global chunk c'^((row>>1)&3)
  const int r0 = tid >> 2;                       // rows 0..63
  const int c0 = (tid & 3) ^ ((r0 >> 1) & 3);
  const int r1 = (256 + tid) >> 2;               // rows 64..127
  const int c1 = (tid & 3) ^ ((r1 >> 1) & 3);

  const size_t abase = (size_t)row0 * DIM;
  const size_t bbase = (size_t)col0 * DIM;

  for (int kt = 0; kt < DIM / 32; ++kt) {
    const int k0 = kt * 32;
    __syncthreads();
    gl16(A + abase + (size_t)r0 * DIM + k0 + c0 * 8, &As[w * 512]);
    gl16(A + abase + (size_t)r1 * DIM + k0 + c1 * 8, &As[2048 + w * 512]);
    gl16(B + bbase + (size_t)r0 * DIM + k0 + c0 * 8, &Bs[w * 512]);
    gl16(B + bbase + (size_t)r1 * DIM + k0 + c1 * 8, &Bs[2048 + w * 512]);
    __syncthreads();

    short8 af[4], bfv[4];
#pragma unroll
    for (int mf = 0; mf < 4; ++mf) {
      const int ra = wr * 64 + mf * 16 + fr;
      const int c = kq ^ ((ra >> 1) & 3);
      af[mf] = *reinterpret_cast<const short8*>(&As[ra * 32 + c * 8]);
    }
#pragma unroll
    for (int nf = 0; nf < 4; ++nf) {
      const int rb = wc * 64 + nf * 16 + fr;
      const int c = kq ^ ((rb >> 1) & 3);
      bfv[nf] = *reinterpret_cast<const short8*>(&Bs[rb * 32 + c * 8]);
    }
#pragma unroll
    for (int mf = 0; mf < 4; ++mf)
#pragma unroll
      for (int nf = 0; nf < 4; ++nf)
        acc[mf][nf] = __builtin_amdgcn_mfma_f32_16x16x32_bf16(af[mf], bfv[nf],
                                                              acc[mf][nf], 0, 0, 0);
  }

  // Epilogue: tanh(C + q[b][e]) * V[e], reduce over this block's 128 e's per row.
#pragma unroll
  for (int mf = 0; mf < 4; ++mf) {
#pragma unroll
    for (int reg = 0; reg < 4; ++reg) {
      const int m_loc = wr * 64 + mf * 16 + kq * 4 + reg;
      const int b = m_loc & 31;
      float part = 0.f;
#pragma unroll
      for (int nf = 0; nf < 4; ++nf) {
        const int e = col0 + wc * 64 + nf * 16 + fr;
        float c = acc[mf][nf][reg];
        part += tanhf(c + q[b * DIM + e]) * V[e];
      }
#pragma unroll
      for (int off = 8; off >= 1; off >>= 1) part += __shfl_xor(part, off);
      if (fr == 0) red[wc][m_loc] = part;
    }
  }
  __syncthreads();
  if (tid < 128)
    lpart[(size_t)(row0 + tid) * NT + nt] = red[0][tid] + red[1][tid];
}

// ---------------- fallback GEMM (round-1, fp32 A with inline convert) ----------------
__global__ __launch_bounds__(256) void gemm_fused(const float* __restrict__ enc,
                                                  const unsigned short* __restrict__ Wbf,
                                                  const float* __restrict__ q,
                                                  const float* __restrict__ V,
                                                  float* __restrict__ lpart) {
  __shared__ unsigned short As[128][56];
  __shared__ unsigned short Bs[128][56];
  __shared__ float red[2][128];

  const int bx = blockIdx.x;
  const int nt = bx & (NT - 1);
  const int mt = bx >> 3;
  const int row0 = mt * 128, col0 = nt * 128;
  const int tid = threadIdx.x;
  const int lane = tid & 63;
  const int w = tid >> 6;
  const int wr = w >> 1, wc = w & 1;
  const int fr = lane & 15, kq = lane >> 4;

  f32x4 acc[4][4];
#pragma unroll
  for (int i = 0; i < 4; ++i)
#pragma unroll
    for (int j = 0; j < 4; ++j) acc[i][j] = (f32x4)(0.f);

  const int trow = tid >> 3;
  const int tc4 = tid & 7;

  for (int kt = 0; kt < DIM / 32; ++kt) {
    const int k0 = kt * 32;
    __syncthreads();
#pragma unroll
    for (int it = 0; it < 4; ++it) {
      const int r = trow + it * 32;
      float4 va = *reinterpret_cast<const float4*>(
          &enc[(size_t)(row0 + r) * DIM + k0 + tc4 * 4]);
      ushort4 ua;
      ua.x = f2bf(va.x); ua.y = f2bf(va.y); ua.z = f2bf(va.z); ua.w = f2bf(va.w);
      *reinterpret_cast<ushort4*>(&As[r][tc4 * 4]) = ua;
      ushort4 ub = *reinterpret_cast<const ushort4*>(
          &Wbf[(size_t)(col0 + r) * DIM + k0 + tc4 * 4]);
      *reinterpret_cast<ushort4*>(&Bs[r][tc4 * 4]) = ub;
    }
    __syncthreads();

    short8 af[4], bfv[4];
#pragma unroll
    for (int mf = 0; mf < 4; ++mf)
      af[mf] = *reinterpret_cast<const short8*>(&As[wr * 64 + mf * 16 + fr][kq * 8]);
#pragma unroll
    for (int nf = 0; nf < 4; ++nf)
      bfv[nf] = *reinterpret_cast<const short8*>(&Bs[wc * 64 + nf * 16 + fr][kq * 8]);
#pragma unroll
    for (int mf = 0; mf < 4; ++mf)
#pragma unroll
      for (int nf = 0; nf < 4; ++nf)
        acc[mf][nf] = __builtin_amdgcn_mfma_f32_16x16x32_bf16(af[mf], bfv[nf],
                                                              acc[mf][nf], 0, 0, 0);
  }

#pragma unroll
  for (int mf = 0; mf < 4; ++mf) {
#pragma unroll
    for (int reg = 0; reg < 4; ++reg) {
      const int m_loc = wr * 64 + mf * 16 + kq * 4 + reg;
      const int b = m_loc & 31;
      float part = 0.f;
#pragma unroll
      for (int nf = 0; nf < 4; ++nf) {
        const int e = col0 + wc * 64 + nf * 16 + fr;
        float c = acc[mf][nf][reg];
        part += tanhf(c + q[b * DIM + e]) * V[e];
      }
#pragma unroll
      for (int off = 8; off >= 1; off >>= 1) part += __shfl_xor(part, off);
      if (fr == 0) red[wc][m_loc] = part;
    }
  }
  __syncthreads();
  if (tid < 128)
    lpart[(size_t)(row0 + tid) * NT + nt] = red[0][tid] + red[1][tid];
}

// ---------------- softmax over seq per batch ----------------
__global__ __launch_bounds__(256) void softmax_k(const float* __restrict__ lpart,
                                                 float* __restrict__ alpha) {
  const int b = blockIdx.x;
  __shared__ float lv[SEQ];
  __shared__ float sred[4];
  const int tid = threadIdx.x;
  float mx = -1e30f;
  for (int s = tid; s < SEQ; s += 256) {
    const float* p = &lpart[(size_t)(s * BATCH + b) * NT];
    float v = 0.f;
#pragma unroll
    for (int t = 0; t < NT; ++t) v += p[t];
    lv[s] = v;
    mx = fmaxf(mx, v);
  }
#pragma unroll
  for (int off = 32; off >= 1; off >>= 1) mx = fmaxf(mx, __shfl_xor(mx, off));
  if ((tid & 63) == 0) sred[tid >> 6] = mx;
  __syncthreads();
  mx = fmaxf(fmaxf(sred[0], sred[1]), fmaxf(sred[2], sred[3]));
  __syncthreads();
  float sm = 0.f;
  for (int s = tid; s < SEQ; s += 256) {
    float e = expf(lv[s] - mx);
    lv[s] = e;
    sm += e;
  }
#pragma unroll
  for (int off = 32; off >= 1; off >>= 1) sm += __shfl_xor(sm, off);
  if ((tid & 63) == 0) sred[tid >> 6] = sm;
  __syncthreads();
  const float inv = 1.f / (sred[0] + sred[1] + sred[2] + sred[3]);
  for (int s = tid; s < SEQ; s += 256)
    alpha[(size_t)b * SEQ + s] = lv[s] * inv;
}

// ---------------- context partials: sum_s alpha[b,s]*enc[s,b,:] ----------------
__global__ __launch_bounds__(256) void ctx_part_k(const float* __restrict__ enc,
                                                  const float* __restrict__ alpha,
                                                  float* __restrict__ cpart) {
  const int blk = blockIdx.x;
  const int b = blk & 31;
  const int ch = blk >> 5;
  const int tid = threadIdx.x;
  const int s0 = ch * (SEQ / NCH);
  float4 acc = make_float4(0.f, 0.f, 0.f, 0.f);
#pragma unroll 4
  for (int i = 0; i < SEQ / NCH; ++i) {
    const int s = s0 + i;
    const float a = alpha[(size_t)b * SEQ + s];
    float4 v = *reinterpret_cast<const float4*>(
        &enc[((size_t)s * BATCH + b) * DIM + tid * 4]);
    acc.x += a * v.x; acc.y += a * v.y; acc.z += a * v.z; acc.w += a * v.w;
  }
  *reinterpret_cast<float4*>(&cpart[((size_t)ch * BATCH + b) * DIM + tid * 4]) = acc;
}

__global__ __launch_bounds__(256) void ctxred_k(const float* __restrict__ cpart,
                                                float* __restrict__ out) {
  int i = blockIdx.x * 256 + threadIdx.x;
  float s = 0.f;
#pragma unroll
  for (int ch = 0; ch < NCH; ++ch) s += cpart[(size_t)ch * 32768 + i];
  out[i] = s;
}

extern "C" void kernel_launch(void* const* d_in, const int* in_sizes, int n_in,
                              void* d_out, int out_size, void* d_ws, size_t ws_size,
                              hipStream_t stream) {
  const float* dh   = (const float*)d_in[0];   // (32,1,1024)
  const float* enc  = (const float*)d_in[1];   // (2048,32,1024)
  const float* Wenc = (const float*)d_in[2];   // (1024,1024)
  const float* Wdec = (const float*)d_in[3];   // (1024,1024)
  const float* Vatt = (const float*)d_in[4];   // (1,1024)
  float* out = (float*)d_out;                  // [0,32768) context, [32768,98304) alpha

  float* ws = (float*)d_ws;
  float* q      = ws;                                   // 32768
  float* qpart  = ws + 32768;                           // 262144
  float* lpart  = ws + 294912;                          // 65536*8 = 524288
  float* cpart  = ws + 819200;                          // 16*32768 = 524288
  unsigned short* Wbf   = (unsigned short*)(ws + 1343488);  // 1Mi shorts (524288 f)
  unsigned short* encbf = (unsigned short*)(ws + 1867776);  // 64Mi shorts (33554432 f)
  const size_t need = (size_t)(1867776 + 33554432) * sizeof(float); // ~141.7 MB

  conv_bf16_k<<<dim3(512),  dim3(256), 0, stream>>>(Wenc, Wbf);
  qpart_k    <<<dim3(32),   dim3(256), 0, stream>>>(dh, Wdec, qpart);
  qred_k     <<<dim3(128),  dim3(256), 0, stream>>>(qpart, q);

  if (ws_size >= need) {
    conv_bf16_k<<<dim3(32768), dim3(256), 0, stream>>>(enc, encbf);
    gemm_fused2<<<dim3(MROWS / 128 * NT), dim3(256), 0, stream>>>(encbf, Wbf, q, Vatt, lpart);
  } else {
    gemm_fused <<<dim3(MROWS / 128 * NT), dim3(256), 0, stream>>>(enc, Wbf, q, Vatt, lpart);
  }

  softmax_k  <<<dim3(BATCH),      dim3(256), 0, stream>>>(lpart, out + 32768);
  ctx_part_k <<<dim3(BATCH*NCH),  dim3(256), 0, stream>>>(enc, out + 32768, cpart);
  ctxred_k   <<<dim3(128),        dim3(256), 0, stream>>>(cpart, out);
}

// Round 3
// 304.041 us; speedup vs baseline: 1.4757x; 1.3438x over previous
//
#include <hip/hip_runtime.h>
#include <hip/hip_bf16.h>
#include <math.h>

#define SEQ   2048
#define BATCH 32
#define DIM   1024
#define MROWS (SEQ*BATCH)   // 65536 rows, r = s*32 + b
#define NT2   4             // 1024 / 256 N-tiles
#define NCH   16            // context s-chunks
#define NKT   16            // K-tiles of 64

typedef __attribute__((ext_vector_type(8))) short short8;
typedef __attribute__((ext_vector_type(8))) unsigned short u16x8;
typedef __attribute__((ext_vector_type(4))) float f32x4;

__device__ __forceinline__ unsigned short f2bf(float f) {
  unsigned u = __builtin_bit_cast(unsigned, f);
  u += 0x7FFFu + ((u >> 16) & 1u);      // round-to-nearest-even
  return (unsigned short)(u >> 16);
}

// async global -> LDS, 16 B per lane (dest = wave-uniform base + lane*16)
__device__ __forceinline__ void gl16(const unsigned short* g, unsigned short* l) {
  __builtin_amdgcn_global_load_lds(
      (const __attribute__((address_space(1))) unsigned int*)g,
      (__attribute__((address_space(3))) unsigned int*)l, 16, 0, 0);
}

// ---------------- fp32 -> bf16 bulk convert (8 elems/thread) ----------------
__global__ __launch_bounds__(256) void conv_bf16_k(const float* __restrict__ src,
                                                   unsigned short* __restrict__ dst) {
  size_t i = ((size_t)blockIdx.x * 256 + threadIdx.x) * 8;
  float4 a = *reinterpret_cast<const float4*>(src + i);
  float4 b = *reinterpret_cast<const float4*>(src + i + 4);
  u16x8 o;
  o[0] = f2bf(a.x); o[1] = f2bf(a.y); o[2] = f2bf(a.z); o[3] = f2bf(a.w);
  o[4] = f2bf(b.x); o[5] = f2bf(b.y); o[6] = f2bf(b.z); o[7] = f2bf(b.w);
  *reinterpret_cast<u16x8*>(dst + i) = o;
}

// ---------------- q[b,e] = sum_d dh[b,d] * W_dec[e,d] ----------------
__global__ __launch_bounds__(256) void qpart_k(const float* __restrict__ dh,
                                               const float* __restrict__ Wd,
                                               float* __restrict__ qpart) {
  const int bx = blockIdx.x;        // 32 blocks
  const int eb = bx & 3;            // 4 e-blocks of 256
  const int dc = bx >> 2;           // 8 d-chunks of 128
  __shared__ float ldh[BATCH][128];
  const int tid = threadIdx.x;
#pragma unroll
  for (int i = 0; i < 4; ++i) {
    int idx = tid + i * 256;
    int bb = idx >> 5, d4 = idx & 31;
    float4 v = *reinterpret_cast<const float4*>(&dh[(size_t)bb * DIM + dc * 128 + d4 * 4]);
    *reinterpret_cast<float4*>(&ldh[bb][d4 * 4]) = v;
  }
  __syncthreads();
  const int e = eb * 256 + tid;
  float acc[BATCH];
#pragma unroll
  for (int b = 0; b < BATCH; ++b) acc[b] = 0.f;
  for (int d4 = 0; d4 < 32; ++d4) {
    float4 w = *reinterpret_cast<const float4*>(&Wd[(size_t)e * DIM + dc * 128 + d4 * 4]);
#pragma unroll
    for (int b = 0; b < BATCH; ++b) {
      float4 h = *reinterpret_cast<const float4*>(&ldh[b][d4 * 4]);
      acc[b] += w.x * h.x + w.y * h.y + w.z * h.z + w.w * h.w;
    }
  }
#pragma unroll
  for (int b = 0; b < BATCH; ++b)
    qpart[((size_t)dc * BATCH + b) * DIM + e] = acc[b];
}

__global__ __launch_bounds__(256) void qred_k(const float* __restrict__ qpart,
                                              float* __restrict__ q) {
  int i = blockIdx.x * 256 + threadIdx.x;
  float s = 0.f;
#pragma unroll
  for (int dc = 0; dc < 8; ++dc) s += qpart[(size_t)dc * 32768 + i];
  q[i] = s;
}

// ============ 256^2 8-phase fused GEMM ============
// A = enc bf16 [65536][1024], B = W_enc bf16 [1024][1024] (both K-major).
// lpart[r][nt] = sum_{e in 256-tile} tanh(sum_d A[r][d]B[e][d] + q[r&31][e]) * V[e]
#define BARR  __builtin_amdgcn_s_barrier()
#define LGKM0 do { asm volatile("s_waitcnt lgkmcnt(0)" ::: "memory"); \
                   __builtin_amdgcn_sched_barrier(0); } while (0)
#define VMC4  asm volatile("s_waitcnt vmcnt(4)" ::: "memory")
#define VMC0  asm volatile("s_waitcnt vmcnt(0)" ::: "memory")

// stage half-tile h of K-tile t for operand (isB) into buf (t&1); 2 x gl16
#define STAGE(t, isB, h) do {                                                   \
    const unsigned short* gb_ = ((isB) ? Bbase : Abase)                         \
        + (size_t)(h) * 131072 + (size_t)(t) * 64;                              \
    char* lb_ = arena + ((t) & 1) * 65536 + ((isB) ? 32768 : 0) + (h) * 16384;  \
    gl16(gb_ + (size_t)r0 * 1024 + c0 * 8, (unsigned short*)lb_ + w * 512);     \
    gl16(gb_ + (size_t)r1 * 1024 + c1 * 8,                                      \
         (unsigned short*)(lb_ + 8192) + w * 512);                              \
  } while (0)

#define LOAD_A(d, MH) do {                                                      \
    const char* bA_ = arena + (d) * 65536;                                      \
    _Pragma("unroll") for (int i_ = 0; i_ < 4; ++i_)                            \
    _Pragma("unroll") for (int ks_ = 0; ks_ < 2; ++ks_) {                       \
      int ra_ = wr * 128 + ((MH) * 4 + i_) * 16 + fr;                           \
      int hh_ = ra_ >> 7, rr_ = ra_ & 127;                                      \
      int cb_ = (ks_ * 64 + kq * 16) ^ ((rr_ & 7) << 4);                        \
      a[i_][ks_] = *(const short8*)(bA_ + hh_ * 16384 + rr_ * 128 + cb_);       \
    } } while (0)

#define LOAD_B(d, NH) do {                                                      \
    const char* bB_ = arena + (d) * 65536 + 32768;                              \
    _Pragma("unroll") for (int j_ = 0; j_ < 2; ++j_)                            \
    _Pragma("unroll") for (int ks_ = 0; ks_ < 2; ++ks_) {                       \
      int rb_ = wc * 64 + ((NH) * 2 + j_) * 16 + fr;                            \
      int hh_ = rb_ >> 7, rr_ = rb_ & 127;                                      \
      int cb_ = (ks_ * 64 + kq * 16) ^ ((rr_ & 7) << 4);                        \
      b[NH][j_][ks_] = *(const short8*)(bB_ + hh_ * 16384 + rr_ * 128 + cb_);   \
    } } while (0)

#define DO_QUAD(MH, NH) do {                                                    \
    __builtin_amdgcn_s_setprio(1);                                              \
    _Pragma("unroll") for (int i_ = 0; i_ < 4; ++i_)                            \
    _Pragma("unroll") for (int j_ = 0; j_ < 2; ++j_)                            \
    _Pragma("unroll") for (int ks_ = 0; ks_ < 2; ++ks_)                         \
      acc[(MH) * 4 + i_][(NH) * 2 + j_] =                                       \
          __builtin_amdgcn_mfma_f32_16x16x32_bf16(                              \
              a[i_][ks_], b[NH][j_][ks_], acc[(MH) * 4 + i_][(NH) * 2 + j_],    \
              0, 0, 0);                                                         \
    __builtin_amdgcn_s_setprio(0);                                              \
  } while (0)

__global__ __launch_bounds__(512, 2) void gemm8p(const unsigned short* __restrict__ A,
                                                 const unsigned short* __restrict__ B,
                                                 const float* __restrict__ q,
                                                 const float* __restrict__ V,
                                                 float* __restrict__ lpart) {
  __shared__ __align__(16) char arena[131072];   // 2 bufs x (A 32KB | B 32KB)

  const int bid = blockIdx.x;
  const int wg = (bid & 7) * 128 + (bid >> 3);   // XCD-bijective (1024 % 8 == 0)
  const int mt = wg >> 2, nt = wg & 3;
  const int row0 = mt * 256, col0 = nt * 256;
  const int tid = threadIdx.x;
  const int lane = tid & 63, w = tid >> 6;
  const int wr = w >> 2, wc = w & 3;             // 2 x 4 waves, each 128x64 out
  const int fr = lane & 15, kq = lane >> 4;

  // staging lane geometry: unit u covers LDS 16B-slot u; row u>>3, chunk (u&7)^(row&7)
  const int u0 = tid,        r0 = u0 >> 3;
  const int c0 = (u0 & 7) ^ (r0 & 7);
  const int u1 = 512 + tid,  r1 = u1 >> 3;       // rows 64..127 of the half
  const int c1 = (u1 & 7) ^ (r1 & 7);

  const unsigned short* Abase = A + (size_t)row0 * DIM;
  const unsigned short* Bbase = B + (size_t)col0 * DIM;

  f32x4 acc[8][4];
#pragma unroll
  for (int i = 0; i < 8; ++i)
#pragma unroll
    for (int j = 0; j < 4; ++j) acc[i][j] = (f32x4)(0.f);

  short8 a[4][2];        // current A half: 4 mf x 2 k-slices
  short8 b[2][2][2];     // both B halves: nh x nf x ks

  // ---- prologue: K0 fully + K1.{Ah0,Bh0}; drain; barrier ----
  STAGE(0, 0, 0); STAGE(0, 0, 1); STAGE(0, 1, 0); STAGE(0, 1, 1);
  STAGE(1, 0, 0); STAGE(1, 1, 0);
  VMC0;
  BARR;

#pragma unroll 1
  for (int t2 = 0; t2 < NKT; t2 += 2) {
    const bool last = (t2 == NKT - 2);
    // ---- phase 1: tile t2 (buf0), quad (M0,N0) ----
    LOAD_A(0, 0); LOAD_B(0, 0);
    STAGE(t2 + 1, 0, 1);                       // (t+1).A.h1
    BARR; LGKM0; DO_QUAD(0, 0); BARR;
    // ---- phase 2: (M0,N1) ----
    LOAD_B(0, 1);
    STAGE(t2 + 1, 1, 1);                       // (t+1).B.h1
    BARR; LGKM0; DO_QUAD(0, 1); BARR;
    // ---- phase 3: (M1,N0) ----
    LOAD_A(0, 1);
    if (!last) STAGE(t2 + 2, 0, 0);            // (t+2).A.h0
    BARR; LGKM0; DO_QUAD(1, 0); BARR;
    // ---- phase 4: (M1,N1) + K-tile wait ----
    if (!last) { STAGE(t2 + 2, 1, 0); VMC4; } else { VMC0; }
    BARR; LGKM0; DO_QUAD(1, 1); BARR;
    // ---- phase 5: tile t2+1 (buf1), quad (M0,N0) ----
    LOAD_A(1, 0); LOAD_B(1, 0);
    if (!last) STAGE(t2 + 2, 0, 1);            // (t+2).A.h1
    BARR; LGKM0; DO_QUAD(0, 0); BARR;
    // ---- phase 6: (M0,N1) ----
    LOAD_B(1, 1);
    if (!last) STAGE(t2 + 2, 1, 1);            // (t+2).B.h1
    BARR; LGKM0; DO_QUAD(0, 1); BARR;
    // ---- phase 7: (M1,N0) ----
    LOAD_A(1, 1);
    if (!last) STAGE(t2 + 3, 0, 0);            // (t+3).A.h0
    BARR; LGKM0; DO_QUAD(1, 0); BARR;
    // ---- phase 8: (M1,N1) + K-tile wait ----
    if (!last) { STAGE(t2 + 3, 1, 0); VMC4; }  // (t+3).B.h0
    BARR; LGKM0; DO_QUAD(1, 1); BARR;
  }

  // ================= epilogue =================
  __syncthreads();                 // staging LDS dead; overlay q/V/red
  float* qld = (float*)arena;                    // [32][260] padded
  float* vld = (float*)(arena + 33280);          // [256]
  float* red = (float*)(arena + 34304);          // [4][256]
#pragma unroll
  for (int i = 0; i < 4; ++i) {
    int id = i * 512 + tid;                      // 2048 float4s
    int bb = id >> 6, e4 = id & 63;
    float4 v = *(const float4*)&q[(size_t)bb * DIM + col0 + e4 * 4];
    *(float4*)&qld[bb * 260 + e4 * 4] = v;
  }
  if (tid < 64) *(float4*)&vld[tid * 4] = *(const float4*)&V[col0 + tid * 4];
  __syncthreads();

#pragma unroll
  for (int mf = 0; mf < 8; ++mf) {
#pragma unroll
    for (int reg = 0; reg < 4; ++reg) {
      const int m_loc = wr * 128 + mf * 16 + kq * 4 + reg;
      const int bb = m_loc & 31;                 // row0 % 32 == 0
      float val = 0.f;
#pragma unroll
      for (int nf = 0; nf < 4; ++nf) {
        const int el = wc * 64 + nf * 16 + fr;
        float x = acc[mf][nf][reg] + qld[bb * 260 + el];
        float g = __expf(2.f * x);               // inf-safe form below
        float tnh = 1.f - 2.f * __builtin_amdgcn_rcpf(g + 1.f);
        val += tnh * vld[el];
      }
      val += __shfl_xor(val, 1); val += __shfl_xor(val, 2);
      val += __shfl_xor(val, 4); val += __shfl_xor(val, 8);
      if (fr == 0) red[wc * 256 + m_loc] = val;
    }
  }
  __syncthreads();
  if (tid < 256) {
    float s = red[tid] + red[256 + tid] + red[512 + tid] + red[768 + tid];
    lpart[(size_t)(row0 + tid) * NT2 + nt] = s;
  }
}

// ---------------- softmax over seq per batch ----------------
__global__ __launch_bounds__(256) void softmax_k(const float* __restrict__ lpart,
                                                 float* __restrict__ alpha) {
  const int b = blockIdx.x;
  __shared__ float lv[SEQ];
  __shared__ float sred[4];
  const int tid = threadIdx.x;
  float mx = -1e30f;
  for (int s = tid; s < SEQ; s += 256) {
    const float* p = &lpart[(size_t)(s * BATCH + b) * NT2];
    float v = p[0] + p[1] + p[2] + p[3];
    lv[s] = v;
    mx = fmaxf(mx, v);
  }
#pragma unroll
  for (int off = 32; off >= 1; off >>= 1) mx = fmaxf(mx, __shfl_xor(mx, off));
  if ((tid & 63) == 0) sred[tid >> 6] = mx;
  __syncthreads();
  mx = fmaxf(fmaxf(sred[0], sred[1]), fmaxf(sred[2], sred[3]));
  __syncthreads();
  float sm = 0.f;
  for (int s = tid; s < SEQ; s += 256) {
    float e = expf(lv[s] - mx);
    lv[s] = e;
    sm += e;
  }
#pragma unroll
  for (int off = 32; off >= 1; off >>= 1) sm += __shfl_xor(sm, off);
  if ((tid & 63) == 0) sred[tid >> 6] = sm;
  __syncthreads();
  const float inv = 1.f / (sred[0] + sred[1] + sred[2] + sred[3]);
  for (int s = tid; s < SEQ; s += 256)
    alpha[(size_t)b * SEQ + s] = lv[s] * inv;
}

// ---------------- context partials: sum_s alpha[b,s]*enc[s,b,:] ----------------
__global__ __launch_bounds__(256) void ctx_part_k(const float* __restrict__ enc,
                                                  const float* __restrict__ alpha,
                                                  float* __restrict__ cpart) {
  const int blk = blockIdx.x;
  const int b = blk & 31;
  const int ch = blk >> 5;
  const int tid = threadIdx.x;
  const int s0 = ch * (SEQ / NCH);
  float4 acc = make_float4(0.f, 0.f, 0.f, 0.f);
#pragma unroll 4
  for (int i = 0; i < SEQ / NCH; ++i) {
    const int s = s0 + i;
    const float a = alpha[(size_t)b * SEQ + s];
    float4 v = *reinterpret_cast<const float4*>(
        &enc[((size_t)s * BATCH + b) * DIM + tid * 4]);
    acc.x += a * v.x; acc.y += a * v.y; acc.z += a * v.z; acc.w += a * v.w;
  }
  *reinterpret_cast<float4*>(&cpart[((size_t)ch * BATCH + b) * DIM + tid * 4]) = acc;
}

__global__ __launch_bounds__(256) void ctxred_k(const float* __restrict__ cpart,
                                                float* __restrict__ out) {
  int i = blockIdx.x * 256 + threadIdx.x;
  float s = 0.f;
#pragma unroll
  for (int ch = 0; ch < NCH; ++ch) s += cpart[(size_t)ch * 32768 + i];
  out[i] = s;
}

extern "C" void kernel_launch(void* const* d_in, const int* in_sizes, int n_in,
                              void* d_out, int out_size, void* d_ws, size_t ws_size,
                              hipStream_t stream) {
  const float* dh   = (const float*)d_in[0];   // (32,1,1024)
  const float* enc  = (const float*)d_in[1];   // (2048,32,1024)
  const float* Wenc = (const float*)d_in[2];   // (1024,1024)
  const float* Wdec = (const float*)d_in[3];   // (1024,1024)
  const float* Vatt = (const float*)d_in[4];   // (1,1024)
  float* out = (float*)d_out;                  // [0,32768) context, [32768,98304) alpha

  float* ws = (float*)d_ws;
  float* q      = ws;                                   // 32768
  float* qpart  = ws + 32768;                           // 262144
  float* lpart  = ws + 294912;                          // 65536*4 = 262144
  float* cpart  = ws + 819200;                          // 16*32768 = 524288
  unsigned short* Wbf   = (unsigned short*)(ws + 1343488);  // 1Mi bf16
  unsigned short* encbf = (unsigned short*)(ws + 1867776);  // 64Mi bf16

  conv_bf16_k<<<dim3(512),   dim3(256), 0, stream>>>(Wenc, Wbf);
  qpart_k    <<<dim3(32),    dim3(256), 0, stream>>>(dh, Wdec, qpart);
  qred_k     <<<dim3(128),   dim3(256), 0, stream>>>(qpart, q);
  conv_bf16_k<<<dim3(32768), dim3(256), 0, stream>>>(enc, encbf);
  gemm8p     <<<dim3(1024),  dim3(512), 0, stream>>>(encbf, Wbf, q, Vatt, lpart);
  softmax_k  <<<dim3(BATCH),     dim3(256), 0, stream>>>(lpart, out + 32768);
  ctx_part_k <<<dim3(BATCH*NCH), dim3(256), 0, stream>>>(enc, out + 32768, cpart);
  ctxred_k   <<<dim3(128),       dim3(256), 0, stream>>>(cpart, out);
}